// Round 2
// baseline (70.968 us; speedup 1.0000x reference)
//
#include <hip/hip_runtime.h>

// cluster (discriminative) loss: L_var + L_dist, C=4 channels, K=5 labels.
// Labels arrive as int32 (harness converts integer inputs to int*).
// Pass 1: counts[K], sums[K][C]  -> centroids
// Pass 2: per-pixel hinge^2(||mu_lab - x|| - dv) segment-summed by label
// Two tiny single-block kernels do the O(K^2) scalar math.

constexpr int K   = 5;
constexpr int C   = 4;
constexpr int NB  = 1024;   // blocks for the streaming passes
constexpr int TPB = 256;
constexpr int PPT = 8;      // pixels per thread per chunk

__device__ __forceinline__ float wave_reduce_sum(float v) {
#pragma unroll
  for (int off = 32; off > 0; off >>= 1) v += __shfl_down(v, off, 64);
  return v;
}

// ---------------- Pass 1: counts + sums -> partial[25][NB] ----------------
__global__ __launch_bounds__(TPB) void k_stats(
    const float* __restrict__ pred, const int* __restrict__ lab,
    float* __restrict__ partial, int HW) {
  const int tid = threadIdx.x;

  float cnt[K] = {0.f, 0.f, 0.f, 0.f, 0.f};
  float sum[K][C] = {};

  const long long chunk_stride = (long long)NB * TPB * PPT;
  for (long long chunk = (long long)blockIdx.x * TPB * PPT; chunk < HW;
       chunk += chunk_stride) {
    const long long p0 = chunk + (long long)tid * PPT;
    if (p0 + PPT <= HW) {
      int4 la = *reinterpret_cast<const int4*>(lab + p0);
      int4 lb = *reinterpret_cast<const int4*>(lab + p0 + 4);
      int labv[PPT] = {la.x, la.y, la.z, la.w, lb.x, lb.y, lb.z, lb.w};
      float x[PPT][C];
#pragma unroll
      for (int c = 0; c < C; ++c) {
        const float* base = pred + (long long)c * HW + p0;
        float4 a = *reinterpret_cast<const float4*>(base);
        float4 b = *reinterpret_cast<const float4*>(base + 4);
        x[0][c] = a.x; x[1][c] = a.y; x[2][c] = a.z; x[3][c] = a.w;
        x[4][c] = b.x; x[5][c] = b.y; x[6][c] = b.z; x[7][c] = b.w;
      }
#pragma unroll
      for (int p = 0; p < PPT; ++p) {
        const int l = labv[p];
#pragma unroll
        for (int k = 0; k < K; ++k) {
          const float m = (l == k) ? 1.0f : 0.0f;
          cnt[k] += m;
#pragma unroll
          for (int c = 0; c < C; ++c) sum[k][c] = fmaf(m, x[p][c], sum[k][c]);
        }
      }
    } else if (p0 < HW) {  // scalar tail (unused at HW=2^21, kept for safety)
      for (int p = 0; p < PPT && p0 + p < HW; ++p) {
        const int l = lab[p0 + p];
        for (int k = 0; k < K; ++k) {
          const float m = (l == k) ? 1.0f : 0.0f;
          cnt[k] += m;
          for (int c = 0; c < C; ++c)
            sum[k][c] = fmaf(m, pred[(long long)c * HW + p0 + p], sum[k][c]);
        }
      }
    }
  }

  __shared__ float red[TPB / 64][25];
  const int wave = tid >> 6, lane = tid & 63;
#pragma unroll
  for (int j = 0; j < 25; ++j) {
    float v = (j < K) ? cnt[j] : sum[(j - K) >> 2][(j - K) & 3];
    v = wave_reduce_sum(v);
    if (lane == 0) red[wave][j] = v;
  }
  __syncthreads();
  if (tid < 25) {
    float t = red[0][tid] + red[1][tid] + red[2][tid] + red[3][tid];
    partial[tid * NB + blockIdx.x] = t;
  }
}

// ---------- Reduce partials -> finals[0..4]=counts, [5..24]=mu, [25]=L_dist ----------
__global__ __launch_bounds__(TPB) void k_centroids(
    const float* __restrict__ partial, const float* __restrict__ dd_p,
    float* __restrict__ finals) {
  __shared__ float tot[25];
  const int tid = threadIdx.x, wave = tid >> 6, lane = tid & 63;
  for (int col = wave; col < 25; col += TPB / 64) {
    float v = 0.f;
    for (int i = lane; i < NB; i += 64) v += partial[col * NB + i];
    v = wave_reduce_sum(v);
    if (lane == 0) tot[col] = v;
  }
  __syncthreads();
  if (tid == 0) {
    const float dd = dd_p[0];
    float cnt[K], mu[K][C];
#pragma unroll
    for (int k = 0; k < K; ++k) {
      cnt[k] = tot[k];
      const float inv = 1.0f / fmaxf(cnt[k], 1.0f);
#pragma unroll
      for (int c = 0; c < C; ++c) mu[k][c] = tot[K + k * C + c] * inv;
    }
    float ld = 0.f;
#pragma unroll
    for (int a = 0; a < K; ++a) {
#pragma unroll
      for (int b = 0; b < K; ++b) {
        if (a == b) continue;
        float csq = 0.f;
#pragma unroll
        for (int c = 0; c < C; ++c) {
          const float d = mu[a][c] - mu[b][c];
          csq = fmaf(d, d, csq);
        }
        const float cd = csq > 0.f ? sqrtf(csq) : 0.f;
        const float dh = fmaxf(dd - cd, 0.f);
        ld = fmaf(dh, dh, ld);
      }
    }
    ld *= 1.0f / (float)(K * (K - 1));
#pragma unroll
    for (int k = 0; k < K; ++k) finals[k] = cnt[k];
#pragma unroll
    for (int k = 0; k < K; ++k)
#pragma unroll
      for (int c = 0; c < C; ++c) finals[K + k * C + c] = mu[k][c];
    finals[25] = ld;
  }
}

// ---------------- Pass 2: var hinge -> vpartial[K][NB] ----------------
__global__ __launch_bounds__(TPB) void k_var(
    const float* __restrict__ pred, const int* __restrict__ lab,
    const float* __restrict__ finals, const float* __restrict__ dv_p,
    float* __restrict__ vpartial, int HW) {
  __shared__ __align__(16) float smu[K * C];
  if (threadIdx.x < K * C) smu[threadIdx.x] = finals[K + threadIdx.x];
  __syncthreads();
  const float dv = dv_p[0];
  const int tid = threadIdx.x;

  float vs[K] = {};

  const long long chunk_stride = (long long)NB * TPB * PPT;
  for (long long chunk = (long long)blockIdx.x * TPB * PPT; chunk < HW;
       chunk += chunk_stride) {
    const long long p0 = chunk + (long long)tid * PPT;
    if (p0 + PPT <= HW) {
      int4 la = *reinterpret_cast<const int4*>(lab + p0);
      int4 lb = *reinterpret_cast<const int4*>(lab + p0 + 4);
      int labv[PPT] = {la.x, la.y, la.z, la.w, lb.x, lb.y, lb.z, lb.w};
      float x[PPT][C];
#pragma unroll
      for (int c = 0; c < C; ++c) {
        const float* base = pred + (long long)c * HW + p0;
        float4 a = *reinterpret_cast<const float4*>(base);
        float4 b = *reinterpret_cast<const float4*>(base + 4);
        x[0][c] = a.x; x[1][c] = a.y; x[2][c] = a.z; x[3][c] = a.w;
        x[4][c] = b.x; x[5][c] = b.y; x[6][c] = b.z; x[7][c] = b.w;
      }
#pragma unroll
      for (int p = 0; p < PPT; ++p) {
        const int l = labv[p];
        const float4 mu = *reinterpret_cast<const float4*>(&smu[l * C]);
        const float d0 = mu.x - x[p][0];
        const float d1 = mu.y - x[p][1];
        const float d2 = mu.z - x[p][2];
        const float d3 = mu.w - x[p][3];
        float dsq = d0 * d0;
        dsq = fmaf(d1, d1, dsq);
        dsq = fmaf(d2, d2, dsq);
        dsq = fmaf(d3, d3, dsq);
        const float dn = dsq > 0.f ? sqrtf(dsq) : 0.f;
        const float h  = fmaxf(dn - dv, 0.f);
        const float var = h * h;
#pragma unroll
        for (int k = 0; k < K; ++k) vs[k] += (l == k) ? var : 0.f;
      }
    } else if (p0 < HW) {  // scalar tail
      for (int p = 0; p < PPT && p0 + p < HW; ++p) {
        const int l = lab[p0 + p];
        float dsq = 0.f;
        for (int c = 0; c < C; ++c) {
          const float d = smu[l * C + c] - pred[(long long)c * HW + p0 + p];
          dsq = fmaf(d, d, dsq);
        }
        const float dn = dsq > 0.f ? sqrtf(dsq) : 0.f;
        const float h  = fmaxf(dn - dv, 0.f);
        const float var = h * h;
        for (int k = 0; k < K; ++k) vs[k] += (l == k) ? var : 0.f;
      }
    }
  }

  __shared__ float red[TPB / 64][K];
  const int wave = tid >> 6, lane = tid & 63;
#pragma unroll
  for (int j = 0; j < K; ++j) {
    float v = wave_reduce_sum(vs[j]);
    if (lane == 0) red[wave][j] = v;
  }
  __syncthreads();
  if (tid < K) {
    float t = red[0][tid] + red[1][tid] + red[2][tid] + red[3][tid];
    vpartial[tid * NB + blockIdx.x] = t;
  }
}

// ---------------- Final: L_var = sum_k varsum/count /K ; out = L_var + L_dist ----------------
__global__ __launch_bounds__(TPB) void k_final(
    const float* __restrict__ vpartial, const float* __restrict__ finals,
    float* __restrict__ out) {
  __shared__ float tot[K];
  const int tid = threadIdx.x, wave = tid >> 6, lane = tid & 63;
  for (int col = wave; col < K; col += TPB / 64) {
    float v = 0.f;
    for (int i = lane; i < NB; i += 64) v += vpartial[col * NB + i];
    v = wave_reduce_sum(v);
    if (lane == 0) tot[col] = v;
  }
  __syncthreads();
  if (tid == 0) {
    float lvar = 0.f;
#pragma unroll
    for (int k = 0; k < K; ++k) lvar += tot[k] / fmaxf(finals[k], 1.0f);
    lvar *= 1.0f / (float)K;
    out[0] = lvar + finals[25];
  }
}

extern "C" void kernel_launch(void* const* d_in, const int* in_sizes, int n_in,
                              void* d_out, int out_size, void* d_ws, size_t ws_size,
                              hipStream_t stream) {
  const float* pred = (const float*)d_in[0];
  const int*   lab  = (const int*)d_in[1];
  const float* dv   = (const float*)d_in[2];
  const float* dd   = (const float*)d_in[3];
  float*       out  = (float*)d_out;

  const int HW = in_sizes[1];  // 1024*2048 = 2^21

  float* ws     = (float*)d_ws;
  float* part1  = ws;                 // 25 * NB floats
  float* finals = ws + 25 * NB;       // 26 floats (pad to 32)
  float* vpart  = ws + 25 * NB + 32;  // K * NB floats

  k_stats    <<<NB, TPB, 0, stream>>>(pred, lab, part1, HW);
  k_centroids<<<1,  TPB, 0, stream>>>(part1, dd, finals);
  k_var      <<<NB, TPB, 0, stream>>>(pred, lab, finals, dv, vpart, HW);
  k_final    <<<1,  TPB, 0, stream>>>(vpart, finals, out);
}

// Round 3
// 33.255 us; speedup vs baseline: 2.1340x; 2.1340x over previous
//
#include <hip/hip_runtime.h>

// cluster (discriminative) loss: L_var + L_dist, C=4 channels, K=5 labels.
// Labels arrive as int32 (harness converts integer inputs to int*).
// Pass 1: counts[K], sums[K][C]  -> centroids
// Pass 2: per-pixel hinge^2(||mu_lab - x|| - dv) segment-summed by label
// Tail reducers are single-block but fully parallel (float4, 16 waves).

constexpr int K   = 5;
constexpr int C   = 4;
constexpr int NB  = 1024;   // blocks for the streaming passes (multiple of 256)
constexpr int TPB = 256;
constexpr int PPT = 8;      // pixels per thread per chunk
constexpr int RED_TPB = 1024;  // tail reducers: 16 waves

__device__ __forceinline__ float wave_reduce_sum(float v) {
#pragma unroll
  for (int off = 32; off > 0; off >>= 1) v += __shfl_down(v, off, 64);
  return v;
}

// Sum one column of NB floats with one wave: 4 independent float4 loads/lane.
__device__ __forceinline__ float wave_col_sum(const float* __restrict__ colp, int lane) {
  const float4* p4 = reinterpret_cast<const float4*>(colp);
  float4 a0 = p4[lane];
  float4 a1 = p4[lane + 64];
  float4 a2 = p4[lane + 128];
  float4 a3 = p4[lane + 192];
  float s = (a0.x + a0.y) + (a0.z + a0.w);
  s += (a1.x + a1.y) + (a1.z + a1.w);
  s += (a2.x + a2.y) + (a2.z + a2.w);
  s += (a3.x + a3.y) + (a3.z + a3.w);
  return wave_reduce_sum(s);
}

// ---------------- Pass 1: counts + sums -> partial[25][NB] ----------------
__global__ __launch_bounds__(TPB) void k_stats(
    const float* __restrict__ pred, const int* __restrict__ lab,
    float* __restrict__ partial, int HW) {
  const int tid = threadIdx.x;

  float cnt[K] = {0.f, 0.f, 0.f, 0.f, 0.f};
  float sum[K][C] = {};

  const long long chunk_stride = (long long)NB * TPB * PPT;
  for (long long chunk = (long long)blockIdx.x * TPB * PPT; chunk < HW;
       chunk += chunk_stride) {
    const long long p0 = chunk + (long long)tid * PPT;
    if (p0 + PPT <= HW) {
      int4 la = *reinterpret_cast<const int4*>(lab + p0);
      int4 lb = *reinterpret_cast<const int4*>(lab + p0 + 4);
      int labv[PPT] = {la.x, la.y, la.z, la.w, lb.x, lb.y, lb.z, lb.w};
      float x[PPT][C];
#pragma unroll
      for (int c = 0; c < C; ++c) {
        const float* base = pred + (long long)c * HW + p0;
        float4 a = *reinterpret_cast<const float4*>(base);
        float4 b = *reinterpret_cast<const float4*>(base + 4);
        x[0][c] = a.x; x[1][c] = a.y; x[2][c] = a.z; x[3][c] = a.w;
        x[4][c] = b.x; x[5][c] = b.y; x[6][c] = b.z; x[7][c] = b.w;
      }
#pragma unroll
      for (int p = 0; p < PPT; ++p) {
        const int l = labv[p];
#pragma unroll
        for (int k = 0; k < K; ++k) {
          const float m = (l == k) ? 1.0f : 0.0f;
          cnt[k] += m;
#pragma unroll
          for (int c = 0; c < C; ++c) sum[k][c] = fmaf(m, x[p][c], sum[k][c]);
        }
      }
    } else if (p0 < HW) {  // scalar tail (unused at HW=2^21, kept for safety)
      for (int p = 0; p < PPT && p0 + p < HW; ++p) {
        const int l = lab[p0 + p];
        for (int k = 0; k < K; ++k) {
          const float m = (l == k) ? 1.0f : 0.0f;
          cnt[k] += m;
          for (int c = 0; c < C; ++c)
            sum[k][c] = fmaf(m, pred[(long long)c * HW + p0 + p], sum[k][c]);
        }
      }
    }
  }

  __shared__ float red[TPB / 64][25];
  const int wave = tid >> 6, lane = tid & 63;
#pragma unroll
  for (int j = 0; j < 25; ++j) {
    float v = (j < K) ? cnt[j] : sum[(j - K) >> 2][(j - K) & 3];
    v = wave_reduce_sum(v);
    if (lane == 0) red[wave][j] = v;
  }
  __syncthreads();
  if (tid < 25) {
    float t = red[0][tid] + red[1][tid] + red[2][tid] + red[3][tid];
    partial[tid * NB + blockIdx.x] = t;
  }
}

// ---------- Reduce partials -> finals[0..4]=counts, [5..24]=mu, [25]=L_dist ----------
__global__ __launch_bounds__(RED_TPB) void k_centroids(
    const float* __restrict__ partial, const float* __restrict__ dd_p,
    float* __restrict__ finals) {
  __shared__ float tot[25];
  const int tid = threadIdx.x, wave = tid >> 6, lane = tid & 63;
  for (int col = wave; col < 25; col += RED_TPB / 64) {
    float v = wave_col_sum(partial + col * NB, lane);
    if (lane == 0) tot[col] = v;
  }
  __syncthreads();
  if (tid == 0) {
    const float dd = dd_p[0];
    float cnt[K], mu[K][C];
#pragma unroll
    for (int k = 0; k < K; ++k) {
      cnt[k] = tot[k];
      const float inv = 1.0f / fmaxf(cnt[k], 1.0f);
#pragma unroll
      for (int c = 0; c < C; ++c) mu[k][c] = tot[K + k * C + c] * inv;
    }
    float ld = 0.f;
#pragma unroll
    for (int a = 0; a < K; ++a) {
#pragma unroll
      for (int b = 0; b < K; ++b) {
        if (a == b) continue;
        float csq = 0.f;
#pragma unroll
        for (int c = 0; c < C; ++c) {
          const float d = mu[a][c] - mu[b][c];
          csq = fmaf(d, d, csq);
        }
        const float cd = csq > 0.f ? sqrtf(csq) : 0.f;
        const float dh = fmaxf(dd - cd, 0.f);
        ld = fmaf(dh, dh, ld);
      }
    }
    ld *= 1.0f / (float)(K * (K - 1));
#pragma unroll
    for (int k = 0; k < K; ++k) finals[k] = cnt[k];
#pragma unroll
    for (int k = 0; k < K; ++k)
#pragma unroll
      for (int c = 0; c < C; ++c) finals[K + k * C + c] = mu[k][c];
    finals[25] = ld;
  }
}

// ---------------- Pass 2: var hinge -> vpartial[K][NB] ----------------
__global__ __launch_bounds__(TPB) void k_var(
    const float* __restrict__ pred, const int* __restrict__ lab,
    const float* __restrict__ finals, const float* __restrict__ dv_p,
    float* __restrict__ vpartial, int HW) {
  __shared__ __align__(16) float smu[K * C];
  if (threadIdx.x < K * C) smu[threadIdx.x] = finals[K + threadIdx.x];
  __syncthreads();
  const float dv = dv_p[0];
  const int tid = threadIdx.x;

  float vs[K] = {};

  const long long chunk_stride = (long long)NB * TPB * PPT;
  for (long long chunk = (long long)blockIdx.x * TPB * PPT; chunk < HW;
       chunk += chunk_stride) {
    const long long p0 = chunk + (long long)tid * PPT;
    if (p0 + PPT <= HW) {
      int4 la = *reinterpret_cast<const int4*>(lab + p0);
      int4 lb = *reinterpret_cast<const int4*>(lab + p0 + 4);
      int labv[PPT] = {la.x, la.y, la.z, la.w, lb.x, lb.y, lb.z, lb.w};
      float x[PPT][C];
#pragma unroll
      for (int c = 0; c < C; ++c) {
        const float* base = pred + (long long)c * HW + p0;
        float4 a = *reinterpret_cast<const float4*>(base);
        float4 b = *reinterpret_cast<const float4*>(base + 4);
        x[0][c] = a.x; x[1][c] = a.y; x[2][c] = a.z; x[3][c] = a.w;
        x[4][c] = b.x; x[5][c] = b.y; x[6][c] = b.z; x[7][c] = b.w;
      }
#pragma unroll
      for (int p = 0; p < PPT; ++p) {
        const int l = labv[p];
        const float4 mu = *reinterpret_cast<const float4*>(&smu[l * C]);
        const float d0 = mu.x - x[p][0];
        const float d1 = mu.y - x[p][1];
        const float d2 = mu.z - x[p][2];
        const float d3 = mu.w - x[p][3];
        float dsq = d0 * d0;
        dsq = fmaf(d1, d1, dsq);
        dsq = fmaf(d2, d2, dsq);
        dsq = fmaf(d3, d3, dsq);
        const float dn = dsq > 0.f ? sqrtf(dsq) : 0.f;
        const float h  = fmaxf(dn - dv, 0.f);
        const float var = h * h;
#pragma unroll
        for (int k = 0; k < K; ++k) vs[k] += (l == k) ? var : 0.f;
      }
    } else if (p0 < HW) {  // scalar tail
      for (int p = 0; p < PPT && p0 + p < HW; ++p) {
        const int l = lab[p0 + p];
        float dsq = 0.f;
        for (int c = 0; c < C; ++c) {
          const float d = smu[l * C + c] - pred[(long long)c * HW + p0 + p];
          dsq = fmaf(d, d, dsq);
        }
        const float dn = dsq > 0.f ? sqrtf(dsq) : 0.f;
        const float h  = fmaxf(dn - dv, 0.f);
        const float var = h * h;
        for (int k = 0; k < K; ++k) vs[k] += (l == k) ? var : 0.f;
      }
    }
  }

  __shared__ float red[TPB / 64][K];
  const int wave = tid >> 6, lane = tid & 63;
#pragma unroll
  for (int j = 0; j < K; ++j) {
    float v = wave_reduce_sum(vs[j]);
    if (lane == 0) red[wave][j] = v;
  }
  __syncthreads();
  if (tid < K) {
    float t = red[0][tid] + red[1][tid] + red[2][tid] + red[3][tid];
    vpartial[tid * NB + blockIdx.x] = t;
  }
}

// ---------------- Final: L_var = sum_k varsum/count /K ; out = L_var + L_dist ----------------
__global__ __launch_bounds__(RED_TPB) void k_final(
    const float* __restrict__ vpartial, const float* __restrict__ finals,
    float* __restrict__ out) {
  __shared__ float tot[K];
  const int tid = threadIdx.x, wave = tid >> 6, lane = tid & 63;
  if (wave < K) {
    float v = wave_col_sum(vpartial + wave * NB, lane);
    if (lane == 0) tot[wave] = v;
  }
  __syncthreads();
  if (tid == 0) {
    float lvar = 0.f;
#pragma unroll
    for (int k = 0; k < K; ++k) lvar += tot[k] / fmaxf(finals[k], 1.0f);
    lvar *= 1.0f / (float)K;
    out[0] = lvar + finals[25];
  }
}

extern "C" void kernel_launch(void* const* d_in, const int* in_sizes, int n_in,
                              void* d_out, int out_size, void* d_ws, size_t ws_size,
                              hipStream_t stream) {
  const float* pred = (const float*)d_in[0];
  const int*   lab  = (const int*)d_in[1];
  const float* dv   = (const float*)d_in[2];
  const float* dd   = (const float*)d_in[3];
  float*       out  = (float*)d_out;

  const int HW = in_sizes[1];  // 1024*2048 = 2^21

  float* ws     = (float*)d_ws;
  float* part1  = ws;                 // 25 * NB floats
  float* finals = ws + 25 * NB;       // 26 floats (pad to 32)
  float* vpart  = ws + 25 * NB + 32;  // K * NB floats

  k_stats    <<<NB, TPB, 0, stream>>>(pred, lab, part1, HW);
  k_centroids<<<1,  RED_TPB, 0, stream>>>(part1, dd, finals);
  k_var      <<<NB, TPB, 0, stream>>>(pred, lab, finals, dv, vpart, HW);
  k_final    <<<1,  RED_TPB, 0, stream>>>(vpart, finals, out);
}